// Round 2
// baseline (729.891 us; speedup 1.0000x reference)
//
#include <hip/hip_runtime.h>

#define TPB 256
#define TE  2048      // edges per binscatter tile
#define MAXB 6144     // fixed bucket capacity (mean 4081, 32 sigma headroom); mult of 8
#define GRID 512      // 2 blocks/CU x 256 CUs -- MUST stay co-resident (grid barrier)

typedef _Float16 half_t;
typedef _Float16 half4 __attribute__((ext_vector_type(4)));
typedef _Float16 half8 __attribute__((ext_vector_type(8)));
typedef float float8v __attribute__((ext_vector_type(8)));

__host__ __device__ static inline constexpr int cdiv(int a, int b) { return (a + b - 1) / b; }

// ---------------- shared-memory phase overlays (union -> LDS = max = 46.6KB) ----------------
struct SBin {
    int lcnt[256], loffs[256], lcur[256], gres[256], ss[256];
    unsigned int ldata[TE];
};
struct SCsr {
    int ss[256], cnt[256], loffs2[256], lcur2[256], pcnt[256];
    float sdinv[256];
    unsigned short stage[MAXB];
};
template<int DI, int DO, int R, bool WHALF>
struct SConv {
    static constexpr int CT = DO / 4;
    static constexpr int TM = (TPB / CT) * R;
    static constexpr int PX = DI / 4 + 1;
    float4 sW4[WHALF ? 1 : DI * CT];
    half4  sWh[WHALF ? DI * CT : 1];
    float4 sX4[TM * PX];
    int soffs[TM];
    unsigned short snch[TM];
};
struct SHead {
    half_t hW1[128 * 64], hW2[64 * 32], hW3[32 * 16];
    float h1[64 * 65], h2[64 * 33];
};
union SMemAll {
    SBin b;
    SCsr c;
    SConv<16, 32, 4, false>  c1;
    SConv<32, 64, 4, false>  c2;
    SConv<64, 128, 4, true>  c3;
    SHead h;
};

// ---------------- software grid barrier (all GRID blocks co-resident) ----------------
// generation barrier; device-scope atomics (cross-XCD safe per guide G12/G16).
// bounded spin: residency-assumption failure -> wrong answer, not a hang.
__device__ __forceinline__ void gridbar(unsigned int* cnt, unsigned int* gen, unsigned int nb) {
    __syncthreads();
    if (threadIdx.x == 0) {
        unsigned int g = __hip_atomic_load(gen, __ATOMIC_RELAXED, __HIP_MEMORY_SCOPE_AGENT);
        __threadfence();   // release prior global writes (agent scope: L2 wb)
        unsigned int a = __hip_atomic_fetch_add(cnt, 1u, __ATOMIC_ACQ_REL, __HIP_MEMORY_SCOPE_AGENT);
        if (a == nb - 1u) {
            __hip_atomic_store(cnt, 0u, __ATOMIC_RELAXED, __HIP_MEMORY_SCOPE_AGENT);
            __hip_atomic_fetch_add(gen, 1u, __ATOMIC_RELEASE, __HIP_MEMORY_SCOPE_AGENT);
        } else {
            unsigned int spins = 0;
            while (__hip_atomic_load(gen, __ATOMIC_ACQUIRE, __HIP_MEMORY_SCOPE_AGENT) == g) {
                __builtin_amdgcn_s_sleep(2);
                if (++spins > 3000000u) break;   // safety valve
            }
        }
        __threadfence();   // acquire side: invalidate stale L1/L2
    }
    __syncthreads();
}

// ---------------- phase 1: binscatter ----------------
__device__ __forceinline__ void phase_binscatter(SBin& L, const int* __restrict__ src,
        const int* __restrict__ dst, int* __restrict__ bcur,
        unsigned int* __restrict__ gbuf, int e, int nb) {
    const int tid = threadIdx.x;
    const int ntiles = cdiv(e, TE);
    for (int bb = blockIdx.x; bb < ntiles; bb += gridDim.x) {
        const int base = bb * TE;
        const int cnt = min(TE, e - base);
        L.lcnt[tid] = 0;
        __syncthreads();
        unsigned int myv[TE / TPB];
        int myb[TE / TPB];
#pragma unroll
        for (int k = 0; k < TE / TPB; ++k) {
            int j = tid + k * TPB;
            if (j < cnt) {
                int d = dst[base + j], s = src[base + j];
                int b = d >> 8;
                myv[k] = ((unsigned)b << 24) | ((unsigned)(d & 255) << 16) | (unsigned)s;
                myb[k] = b;
                atomicAdd(&L.lcnt[b], 1);
            } else myb[k] = -1;
        }
        __syncthreads();
        {   // scan lcnt -> loffs/lcur
            int v = L.lcnt[tid];
            L.ss[tid] = v;
            __syncthreads();
            for (int d = 1; d < 256; d <<= 1) {
                int x2 = (tid >= d) ? L.ss[tid - d] : 0;
                __syncthreads();
                L.ss[tid] += x2;
                __syncthreads();
            }
            L.loffs[tid] = L.ss[tid] - v;
            L.lcur[tid] = L.ss[tid] - v;
        }
        __syncthreads();
        if (tid < nb && L.lcnt[tid])
            L.gres[tid] = tid * MAXB + atomicAdd(&bcur[tid], L.lcnt[tid]);
#pragma unroll
        for (int k = 0; k < TE / TPB; ++k) {
            if (myb[k] >= 0) {
                int p = atomicAdd(&L.lcur[myb[k]], 1);
                L.ldata[p] = myv[k];
            }
        }
        __syncthreads();
        for (int j = tid; j < cnt; j += TPB) {        // contiguous per-bucket runs
            unsigned int v = L.ldata[j];
            int b = v >> 24;
            gbuf[L.gres[b] + (j - L.loffs[b])] = v & 0xFFFFFFu;
        }
        __syncthreads();
    }
}

// ---------------- phase 2: per-bucket CSR + fused G16 scale ----------------
__device__ __forceinline__ void phase_csr(SCsr& L, const unsigned int* __restrict__ gbuf,
        const int* __restrict__ bcur, const float* __restrict__ x,
        int* __restrict__ offs, unsigned short* __restrict__ nch,
        float* __restrict__ dinv, unsigned short* __restrict__ ssrc,
        half_t* __restrict__ G, int n, int nb) {
    const int t = threadIdx.x;
    for (int bb = blockIdx.x; bb < nb; bb += gridDim.x) {
        const int s0 = bb * MAXB;
        const int m = bcur[bb];
        L.cnt[t] = 0;
        __syncthreads();
        for (int j = t; j < m; j += TPB)
            atomicAdd(&L.cnt[(gbuf[s0 + j] >> 16) & 255], 1);
        __syncthreads();
        {
            int v = L.cnt[t];
            int pv = (v + 7) & ~7;                        // pad to 8
            L.pcnt[t] = pv;
            L.ss[t] = pv;
            __syncthreads();
            for (int d = 1; d < 256; d <<= 1) {
                int x2 = (t >= d) ? L.ss[t - d] : 0;
                __syncthreads();
                L.ss[t] += x2;
                __syncthreads();
            }
            L.loffs2[t] = L.ss[t] - pv;
            L.lcur2[t] = L.ss[t] - pv;
            float di = rsqrtf((float)v + 1.0f);           // +1 self-loop
            L.sdinv[t] = di;
            int node = bb * 256 + t;
            if (node < n) {
                offs[node] = s0 + L.loffs2[t];
                nch[node] = (unsigned short)(pv >> 3);
                dinv[node] = di;
            }
        }
        __syncthreads();
        for (int j = t; j < m; j += TPB) {
            unsigned int v = gbuf[s0 + j];
            int p = atomicAdd(&L.lcur2[(v >> 16) & 255], 1);
            L.stage[p] = (unsigned short)(v & 0xFFFFu);
        }
        __syncthreads();
        {   // sentinel-fill each node's padding (<=7 slots per node)
            int base2 = L.loffs2[t] + L.cnt[t], end2 = L.loffs2[t] + L.pcnt[t];
            for (int q = base2; q < end2; ++q) L.stage[q] = (unsigned short)n;
        }
        __syncthreads();
        const int tot = L.ss[255];                        // sum of padded counts
        for (int j = t; j < tot; j += TPB) ssrc[s0 + j] = L.stage[j];

        // fused scale: G16[node] = x[node] * dinv[node], fp32 -> fp16
        const int base = bb * 256;
        const int cn = min(256, n - base);
        const float4* X4 = (const float4*)x;
        half4* G4 = (half4*)G;
        for (int j = t; j < cn * 4; j += TPB) {
            int nl = j >> 2, k4 = j & 3;
            float4 v = X4[(size_t)(base + nl) * 4 + k4];
            float d = L.sdinv[nl];
            half4 h;
            h.x = (half_t)(v.x * d); h.y = (half_t)(v.y * d);
            h.z = (half_t)(v.z * d); h.w = (half_t)(v.w * d);
            G4[(size_t)(base + nl) * 4 + k4] = h;
        }
        if (bb == 0 && t < 4) G4[(size_t)n * 4 + t] = half4{0, 0, 0, 0};  // sentinel row
        __syncthreads();
    }
}

// ---------------- phases 3-5: fused gather + GEMM conv ----------------
template<int DI, int DO, int R, bool SCALE, bool OUT_HALF, bool WHALF, bool ZSENT, typename SM>
__device__ __forceinline__ void phase_conv(SM& S,
        const int* __restrict__ offs, const unsigned short* __restrict__ nch,
        const unsigned short* __restrict__ ssrc,
        const half_t* __restrict__ G, const float* __restrict__ dinv,
        const float* __restrict__ W, const float* __restrict__ b,
        void* __restrict__ outp, int n) {
    constexpr int CT = DO / 4;
    constexpr int RT = TPB / CT;
    constexpr int TM = RT * R;
    constexpr int K4 = DI / 4;
    constexpr int PX = K4 + 1;       // padded pitch
    constexpr int C  = DI / 8;
    static_assert(TM * C == TPB, "gather/gemm tile mismatch");
    const int tid = threadIdx.x;
    const int ntiles = cdiv(n, TM);

    // stage W once (shared by all tiles this block processes)
    const float4* Wg = (const float4*)W;
    for (int t = tid; t < DI * CT; t += TPB) {
        float4 w = Wg[t];
        if (WHALF) {
            half4 h;
            h.x = (half_t)w.x; h.y = (half_t)w.y;
            h.z = (half_t)w.z; h.w = (half_t)w.w;
            S.sWh[t] = h;
        } else {
            S.sW4[t] = w;
        }
    }

    for (int bb = blockIdx.x; bb < ntiles; bb += gridDim.x) {
        const int r0 = bb * TM;
        if (tid < TM) {
            int row = r0 + tid;
            S.soffs[tid] = (row < n) ? offs[row] : 0;
            S.snch[tid] = (row < n) ? nch[row] : (unsigned short)0;
        }
        __syncthreads();

        // ---- gather phase ----
        {
            int lrow = tid / C;
            int gc = tid - lrow * C;
            int row = r0 + lrow;
            float8v acc;
#pragma unroll
            for (int q = 0; q < 8; ++q) acc[q] = 0.f;
            if (row < n) {
                const half8* Grow = (const half8*)G;
                const unsigned gcU = (unsigned)gc;
                half8 hs = Grow[(unsigned)row * C + gcU];
#pragma unroll
                for (int q = 0; q < 8; ++q) acc[q] = (float)hs[q];
                const int nchunks = S.snch[lrow];
                const uint4* sv = (const uint4*)(ssrc + S.soffs[lrow]);   // 16B aligned
                int k = 0;
                for (; k + 2 <= nchunks; k += 2) {       // 16 gathers in flight
                    uint4 pa = sv[k];
                    uint4 pb = sv[k + 1];
                    unsigned a0 = pa.x & 0xFFFFu, a1 = pa.x >> 16;
                    unsigned a2 = pa.y & 0xFFFFu, a3 = pa.y >> 16;
                    unsigned a4 = pa.z & 0xFFFFu, a5 = pa.z >> 16;
                    unsigned a6 = pa.w & 0xFFFFu, a7 = pa.w >> 16;
                    unsigned b0 = pb.x & 0xFFFFu, b1 = pb.x >> 16;
                    unsigned b2 = pb.y & 0xFFFFu, b3 = pb.y >> 16;
                    unsigned b4 = pb.z & 0xFFFFu, b5 = pb.z >> 16;
                    unsigned b6 = pb.w & 0xFFFFu, b7 = pb.w >> 16;
                    half8 ga0 = Grow[a0 * C + gcU];
                    half8 ga1 = Grow[a1 * C + gcU];
                    half8 ga2 = Grow[a2 * C + gcU];
                    half8 ga3 = Grow[a3 * C + gcU];
                    half8 ga4 = Grow[a4 * C + gcU];
                    half8 ga5 = Grow[a5 * C + gcU];
                    half8 ga6 = Grow[a6 * C + gcU];
                    half8 ga7 = Grow[a7 * C + gcU];
                    half8 gb0 = Grow[b0 * C + gcU];
                    half8 gb1 = Grow[b1 * C + gcU];
                    half8 gb2 = Grow[b2 * C + gcU];
                    half8 gb3 = Grow[b3 * C + gcU];
                    half8 gb4 = Grow[b4 * C + gcU];
                    half8 gb5 = Grow[b5 * C + gcU];
                    half8 gb6 = Grow[b6 * C + gcU];
                    half8 gb7 = Grow[b7 * C + gcU];
#pragma unroll
                    for (int q = 0; q < 8; ++q)
                        acc[q] += (((((float)ga0[q] + (float)ga1[q]) + ((float)ga2[q] + (float)ga3[q]))
                                 +  (((float)ga4[q] + (float)ga5[q]) + ((float)ga6[q] + (float)ga7[q])))
                                 + ((((float)gb0[q] + (float)gb1[q]) + ((float)gb2[q] + (float)gb3[q]))
                                 +  (((float)gb4[q] + (float)gb5[q]) + ((float)gb6[q] + (float)gb7[q]))));
                }
                if (k < nchunks) {                         // odd tail
                    uint4 pk = sv[k];
                    unsigned a0 = pk.x & 0xFFFFu, a1 = pk.x >> 16;
                    unsigned a2 = pk.y & 0xFFFFu, a3 = pk.y >> 16;
                    unsigned a4 = pk.z & 0xFFFFu, a5 = pk.z >> 16;
                    unsigned a6 = pk.w & 0xFFFFu, a7 = pk.w >> 16;
                    half8 g0 = Grow[a0 * C + gcU];
                    half8 g1 = Grow[a1 * C + gcU];
                    half8 g2 = Grow[a2 * C + gcU];
                    half8 g3 = Grow[a3 * C + gcU];
                    half8 g4 = Grow[a4 * C + gcU];
                    half8 g5 = Grow[a5 * C + gcU];
                    half8 g6 = Grow[a6 * C + gcU];
                    half8 g7 = Grow[a7 * C + gcU];
#pragma unroll
                    for (int q = 0; q < 8; ++q)
                        acc[q] += (((float)g0[q] + (float)g1[q]) + ((float)g2[q] + (float)g3[q]))
                                + (((float)g4[q] + (float)g5[q]) + ((float)g6[q] + (float)g7[q]));
                }
                float di = dinv[row];
#pragma unroll
                for (int q = 0; q < 8; ++q) acc[q] *= di;
            }
            S.sX4[lrow * PX + 2 * gc]     = make_float4(acc[0], acc[1], acc[2], acc[3]);
            S.sX4[lrow * PX + 2 * gc + 1] = make_float4(acc[4], acc[5], acc[6], acc[7]);
        }
        __syncthreads();

        // ---- GEMM phase ----
        {
            const int c = tid & (CT - 1);
            const int rg = tid / CT;
            const int rbase = rg * R;
            float4 acc[R];
#pragma unroll
            for (int r = 0; r < R; ++r) acc[r] = make_float4(0.f, 0.f, 0.f, 0.f);

#pragma unroll 2
            for (int k4 = 0; k4 < K4; ++k4) {
                float4 xv[R];
#pragma unroll
                for (int r = 0; r < R; ++r) xv[r] = S.sX4[(rbase + r) * PX + k4];
#pragma unroll
                for (int kk = 0; kk < 4; ++kk) {
                    float4 wv;
                    if (WHALF) {
                        half4 wh = S.sWh[(k4 * 4 + kk) * CT + c];
                        wv = make_float4((float)wh.x, (float)wh.y, (float)wh.z, (float)wh.w);
                    } else {
                        wv = S.sW4[(k4 * 4 + kk) * CT + c];
                    }
#pragma unroll
                    for (int r = 0; r < R; ++r) {
                        float xs = (kk == 0) ? xv[r].x : (kk == 1) ? xv[r].y
                                 : (kk == 2) ? xv[r].z : xv[r].w;
                        acc[r].x += xs * wv.x; acc[r].y += xs * wv.y;
                        acc[r].z += xs * wv.z; acc[r].w += xs * wv.w;
                    }
                }
            }

            float4 bc = ((const float4*)b)[c];
#pragma unroll
            for (int r = 0; r < R; ++r) {
                int row = r0 + rbase + r;
                if (row < n) {
                    float4 o;
                    o.x = fmaxf(acc[r].x + bc.x, 0.f);
                    o.y = fmaxf(acc[r].y + bc.y, 0.f);
                    o.z = fmaxf(acc[r].z + bc.z, 0.f);
                    o.w = fmaxf(acc[r].w + bc.w, 0.f);
                    if (SCALE) {
                        float d = dinv[row];
                        o.x *= d; o.y *= d; o.z *= d; o.w *= d;
                    }
                    if (OUT_HALF) {
                        half4 h;
                        h.x = (half_t)o.x; h.y = (half_t)o.y;
                        h.z = (half_t)o.z; h.w = (half_t)o.w;
                        ((half4*)outp)[(size_t)row * CT + c] = h;
                    } else {
                        ((float4*)outp)[(size_t)row * CT + c] = o;
                    }
                }
            }
        }
        if (ZSENT && OUT_HALF && bb == 0 && tid < CT)
            ((half4*)outp)[(size_t)n * CT + tid] = half4{0, 0, 0, 0};
        __syncthreads();   // protect sX4/soffs reuse across grid-stride tiles
    }
}

// ---------------- phase 6: fused dense head ----------------
__device__ __forceinline__ void phase_head(SHead& L, const half_t* __restrict__ X,
        const float* __restrict__ W1, const float* __restrict__ b1,
        const float* __restrict__ W2, const float* __restrict__ b2,
        const float* __restrict__ W3, const float* __restrict__ b3,
        float* __restrict__ out, int n) {
    const int tid = threadIdx.x;
    const int ntiles = cdiv(n, 64);

    for (int t = tid; t < 128 * 64; t += 256) L.hW1[t] = (half_t)W1[t];
    for (int t = tid; t < 64 * 32; t += 256) L.hW2[t] = (half_t)W2[t];
    for (int t = tid; t < 32 * 16; t += 256) L.hW3[t] = (half_t)W3[t];
    __syncthreads();

    for (int bb = blockIdx.x; bb < ntiles; bb += gridDim.x) {
        const int r0 = bb * 64;
        // ---- stage 1: 128 -> 64 ----
        {
            const int c4 = tid & 15;
            const int rowg = tid >> 4;
            const half8* Xr = (const half8*)X;
            float acc[4][4];
#pragma unroll
            for (int r = 0; r < 4; ++r)
#pragma unroll
                for (int j = 0; j < 4; ++j) acc[r][j] = 0.f;
            for (int k8 = 0; k8 < 16; ++k8) {
                half8 xh[4];
#pragma unroll
                for (int r = 0; r < 4; ++r) {
                    int row = r0 + rowg * 4 + r;
                    if (row < n) xh[r] = Xr[(size_t)row * 16 + k8];
                    else { half8 z; for (int q = 0; q < 8; ++q) z[q] = (half_t)0.f; xh[r] = z; }
                }
#pragma unroll
                for (int q = 0; q < 8; ++q) {
                    int k = k8 * 8 + q;
                    half4 w = *(const half4*)&L.hW1[k * 64 + c4 * 4];
                    float w0 = (float)w.x, w1 = (float)w.y, w2 = (float)w.z, w3 = (float)w.w;
#pragma unroll
                    for (int r = 0; r < 4; ++r) {
                        float xs = (float)xh[r][q];
                        acc[r][0] += xs * w0; acc[r][1] += xs * w1;
                        acc[r][2] += xs * w2; acc[r][3] += xs * w3;
                    }
                }
            }
            float4 bc = ((const float4*)b1)[c4];
#pragma unroll
            for (int r = 0; r < 4; ++r) {
                int rl = rowg * 4 + r;
                L.h1[rl * 65 + c4 * 4 + 0] = fmaxf(acc[r][0] + bc.x, 0.f);
                L.h1[rl * 65 + c4 * 4 + 1] = fmaxf(acc[r][1] + bc.y, 0.f);
                L.h1[rl * 65 + c4 * 4 + 2] = fmaxf(acc[r][2] + bc.z, 0.f);
                L.h1[rl * 65 + c4 * 4 + 3] = fmaxf(acc[r][3] + bc.w, 0.f);
            }
        }
        __syncthreads();

        // ---- stage 2: 64 -> 32 ----
        {
            const int c4 = tid & 7;
            const int rowg = tid >> 3;
            float acc[2][4];
#pragma unroll
            for (int r = 0; r < 2; ++r)
#pragma unroll
                for (int j = 0; j < 4; ++j) acc[r][j] = 0.f;
#pragma unroll 4
            for (int k = 0; k < 64; ++k) {
                half4 w = *(const half4*)&L.hW2[k * 32 + c4 * 4];
                float w0 = (float)w.x, w1 = (float)w.y, w2 = (float)w.z, w3 = (float)w.w;
#pragma unroll
                for (int r = 0; r < 2; ++r) {
                    float xs = L.h1[(rowg * 2 + r) * 65 + k];
                    acc[r][0] += xs * w0; acc[r][1] += xs * w1;
                    acc[r][2] += xs * w2; acc[r][3] += xs * w3;
                }
            }
            float4 bc = ((const float4*)b2)[c4];
#pragma unroll
            for (int r = 0; r < 2; ++r) {
                int rl = rowg * 2 + r;
                L.h2[rl * 33 + c4 * 4 + 0] = fmaxf(acc[r][0] + bc.x, 0.f);
                L.h2[rl * 33 + c4 * 4 + 1] = fmaxf(acc[r][1] + bc.y, 0.f);
                L.h2[rl * 33 + c4 * 4 + 2] = fmaxf(acc[r][2] + bc.z, 0.f);
                L.h2[rl * 33 + c4 * 4 + 3] = fmaxf(acc[r][3] + bc.w, 0.f);
            }
        }
        __syncthreads();

        // ---- stage 3: 32 -> 16 ----
        {
            const int c4 = tid & 3;
            const int rl = tid >> 2;
            float a0 = 0.f, a1 = 0.f, a2 = 0.f, a3 = 0.f;
#pragma unroll 4
            for (int k = 0; k < 32; ++k) {
                half4 w = *(const half4*)&L.hW3[k * 16 + c4 * 4];
                float xs = L.h2[rl * 33 + k];
                a0 += xs * (float)w.x; a1 += xs * (float)w.y;
                a2 += xs * (float)w.z; a3 += xs * (float)w.w;
            }
            int row = r0 + rl;
            if (row < n) {
                float4 bc = ((const float4*)b3)[c4];
                float4 o;
                o.x = fmaxf(a0 + bc.x, 0.f);
                o.y = fmaxf(a1 + bc.y, 0.f);
                o.z = fmaxf(a2 + bc.z, 0.f);
                o.w = fmaxf(a3 + bc.w, 0.f);
                ((float4*)out)[(size_t)row * 4 + c4] = o;
            }
        }
        __syncthreads();   // protect h1/h2 reuse across grid-stride tiles
    }
}

// ---------------- the megakernel: all 6 phases, 5 grid barriers ----------------
__global__ void __launch_bounds__(TPB, 2)
k_mega(const int* __restrict__ src, const int* __restrict__ dst,
       const float* __restrict__ x,
       const float* __restrict__ W1, const float* __restrict__ b1,
       const float* __restrict__ W2, const float* __restrict__ b2,
       const float* __restrict__ W3, const float* __restrict__ b3,
       const float* __restrict__ Wl1, const float* __restrict__ bl1,
       const float* __restrict__ Wl2, const float* __restrict__ bl2,
       const float* __restrict__ Wl3, const float* __restrict__ bl3,
       int* __restrict__ bcur, unsigned int* __restrict__ gcnt, unsigned int* __restrict__ ggen,
       unsigned int* __restrict__ gbuf, int* __restrict__ offs,
       unsigned short* __restrict__ nch, float* __restrict__ dinv,
       unsigned short* __restrict__ ssrc,
       half_t* __restrict__ H1, half_t* __restrict__ H2, half_t* __restrict__ X3h,
       float* __restrict__ out, int n, int e, int nb) {
    __shared__ SMemAll S;
    const unsigned int NB = gridDim.x;

    phase_binscatter(S.b, src, dst, bcur, gbuf, e, nb);
    gridbar(gcnt, ggen, NB);
    phase_csr(S.c, gbuf, bcur, x, offs, nch, dinv, ssrc, H1, n, nb);
    gridbar(gcnt, ggen, NB);
    phase_conv<16, 32, 4, true, true, false, true>(S.c1, offs, nch, ssrc, H1, dinv, W1, b1, H2, n);
    gridbar(gcnt, ggen, NB);
    phase_conv<32, 64, 4, true, true, false, true>(S.c2, offs, nch, ssrc, H2, dinv, W2, b2, H1, n);
    gridbar(gcnt, ggen, NB);
    phase_conv<64, 128, 4, false, true, true, false>(S.c3, offs, nch, ssrc, H1, dinv, W3, b3, X3h, n);
    gridbar(gcnt, ggen, NB);
    phase_head(S.h, X3h, Wl1, bl1, Wl2, bl2, Wl3, bl3, out, n);
}

extern "C" void kernel_launch(void* const* d_in, const int* in_sizes, int n_in,
                              void* d_out, int out_size, void* d_ws, size_t ws_size,
                              hipStream_t stream) {
    const float* x   = (const float*)d_in[0];
    const int*   ei  = (const int*)d_in[1];
    const float* W1  = (const float*)d_in[2];
    const float* bb1 = (const float*)d_in[3];
    const float* W2  = (const float*)d_in[4];
    const float* bb2 = (const float*)d_in[5];
    const float* W3  = (const float*)d_in[6];
    const float* bb3 = (const float*)d_in[7];
    const float* Wl1 = (const float*)d_in[8];
    const float* bl1 = (const float*)d_in[9];
    const float* Wl2 = (const float*)d_in[10];
    const float* bl2 = (const float*)d_in[11];
    const float* Wl3 = (const float*)d_in[12];
    const float* bl3 = (const float*)d_in[13];
    float* out = (float*)d_out;

    const int n = in_sizes[0] / 16;   // 50000
    const int e = in_sizes[1] / 2;    // 800000
    const int* src = ei;
    const int* dst = ei + e;
    const int nb = cdiv(n, 256);      // 196 coarse buckets

    char* p = (char*)d_ws;
    auto alloc = [&](size_t bytes) {
        char* r = p;
        p += (bytes + 255) & ~(size_t)255;
        return r;
    };
    // control block first: bcur[256] + barrier cnt/gen -- zeroed by ONE memset node
    char*           ctrl = alloc(4096);
    int*            bcur = (int*)ctrl;
    unsigned int*   gcnt = (unsigned int*)(ctrl + 1024);
    unsigned int*   ggen = (unsigned int*)(ctrl + 1088);
    float*          dinv = (float*)         alloc((size_t)n * 4);
    int*            offs = (int*)           alloc((size_t)n * 4);
    unsigned short* nch  = (unsigned short*)alloc((size_t)n * 2);
    unsigned int*   gbuf = (unsigned int*)  alloc((size_t)nb * MAXB * 4);
    unsigned short* ssrc = (unsigned short*)alloc((size_t)nb * MAXB * 2);
    half_t*         H1   = (half_t*)        alloc((size_t)(n + 1) * 64 * 2); // G16/G64
    half_t*         H2   = (half_t*)        alloc((size_t)(n + 1) * 32 * 2);
    half_t*         X3h  = (half_t*)        alloc((size_t)n * 128 * 2);

    hipMemsetAsync(ctrl, 0, 4096, stream);
    k_mega<<<GRID, TPB, 0, stream>>>(
        src, dst, x, W1, bb1, W2, bb2, W3, bb3,
        Wl1, bl1, Wl2, bl2, Wl3, bl3,
        bcur, gcnt, ggen, gbuf, offs, nch, dinv, ssrc,
        H1, H2, X3h, out, n, e, nb);
}

// Round 3
// 218.193 us; speedup vs baseline: 3.3452x; 3.3452x over previous
//
#include <hip/hip_runtime.h>

#define TPB 256
#define TE  2048      // edges per binscatter block
#define MAXB 6144     // fixed bucket capacity (mean 4081, 32 sigma headroom); mult of 8

typedef _Float16 half_t;
typedef _Float16 half4 __attribute__((ext_vector_type(4)));
typedef _Float16 half8 __attribute__((ext_vector_type(8)));
typedef float float8v __attribute__((ext_vector_type(8)));

static inline int cdiv(int a, int b) { return (a + b - 1) / b; }

// r5: scattered 4B stores ~16x write-amplified -> contiguous runs only.
// r12: fixed-capacity buckets kill histogram+scans.
// r14: R2 showed software grid barriers cost ~100us (L2 wb/inv on non-coherent
// per-XCD L2s) -> kernel boundaries ARE the cheap barrier. This round: ncnt
// degree table fused into binscatter (csr loses its histogram pass), head
// fused into conv3 (row-local), zero-kernel -> memset node.

__global__ void __launch_bounds__(TPB)
k_binscatter(const int* __restrict__ src, const int* __restrict__ dst,
             int* __restrict__ bcur, int* __restrict__ ncnt,
             unsigned int* __restrict__ gbuf, int e, int nb) {
    __shared__ int lcnt[256], loffs[256], lcur[256], gres[256];
    __shared__ int ss[256];
    __shared__ unsigned int ldata[TE];
    const int tid = threadIdx.x;
    const int base = blockIdx.x * TE;
    const int cnt = min(TE, e - base);
    lcnt[tid] = 0;
    __syncthreads();

    unsigned int myv[TE / TPB];
    int myb[TE / TPB];
#pragma unroll
    for (int k = 0; k < TE / TPB; ++k) {
        int j = tid + k * TPB;
        if (j < cnt) {
            int d = dst[base + j], s = src[base + j];
            int b = d >> 8;
            myv[k] = ((unsigned)b << 24) | ((unsigned)(d & 255) << 16) | (unsigned)s;
            myb[k] = b;
            atomicAdd(&lcnt[b], 1);
            atomicAdd(&ncnt[d], 1);          // global per-node in-degree
        } else myb[k] = -1;
    }
    __syncthreads();
    {
        int v = lcnt[tid];
        ss[tid] = v;
        __syncthreads();
        for (int d = 1; d < 256; d <<= 1) {
            int x2 = (tid >= d) ? ss[tid - d] : 0;
            __syncthreads();
            ss[tid] += x2;
            __syncthreads();
        }
        loffs[tid] = ss[tid] - v;
        lcur[tid] = ss[tid] - v;
    }
    __syncthreads();
    if (tid < nb && lcnt[tid])
        gres[tid] = tid * MAXB + atomicAdd(&bcur[tid], lcnt[tid]);
#pragma unroll
    for (int k = 0; k < TE / TPB; ++k) {
        if (myb[k] >= 0) {
            int p = atomicAdd(&lcur[myb[k]], 1);
            ldata[p] = myv[k];
        }
    }
    __syncthreads();
    for (int j = tid; j < cnt; j += TPB) {        // contiguous per-bucket runs
        unsigned int v = ldata[j];
        int b = v >> 24;
        gbuf[gres[b] + (j - loffs[b])] = v & 0xFFFFFFu;
    }
}

// per-bucket CSR from precomputed degrees: ONE pass over bucket edges.
__global__ void __launch_bounds__(TPB)
k_csr(const unsigned int* __restrict__ gbuf, const int* __restrict__ bcur,
      const int* __restrict__ ncnt, const float* __restrict__ x,
      int* __restrict__ offs, unsigned short* __restrict__ nch,
      float* __restrict__ dinv, unsigned short* __restrict__ ssrc,
      half_t* __restrict__ G, int n, int nb) {
    __shared__ int ss[256], lcur2[256];
    __shared__ float sdinv[256];
    __shared__ unsigned short stage[MAXB];
    const int b = blockIdx.x;
    const int t = threadIdx.x;
    const int s0 = b * MAXB;
    const int m = bcur[b];

    const int v = ncnt[b * 256 + t];              // in-degree (excl self-loop)
    const int pv = (v + 7) & ~7;                  // pad to 8
    ss[t] = pv;
    __syncthreads();
    for (int d = 1; d < 256; d <<= 1) {
        int x2 = (t >= d) ? ss[t - d] : 0;
        __syncthreads();
        ss[t] += x2;
        __syncthreads();
    }
    const int lo = ss[t] - pv;
    lcur2[t] = lo;
    float di = rsqrtf((float)v + 1.0f);           // +1 self-loop
    sdinv[t] = di;
    int node = b * 256 + t;
    if (node < n) {
        offs[node] = s0 + lo;
        nch[node] = (unsigned short)(pv >> 3);
        dinv[node] = di;
    }
    __syncthreads();
    for (int j = t; j < m; j += TPB) {
        unsigned int u = gbuf[s0 + j];
        int p = atomicAdd(&lcur2[(u >> 16) & 255], 1);
        stage[p] = (unsigned short)(u & 0xFFFFu);
    }
    __syncthreads();
    for (int q = lo + v; q < lo + pv; ++q)        // sentinel-fill padding
        stage[q] = (unsigned short)n;
    __syncthreads();
    const int tot = ss[255];
    for (int j = t; j < tot; j += TPB) ssrc[s0 + j] = stage[j];

    // fused scale: G16[node] = x[node] * dinv[node], fp32 -> fp16
    const int base = b * 256;
    const int cn = min(256, n - base);
    const float4* X4 = (const float4*)x;
    half4* G4 = (half4*)G;
    for (int j = t; j < cn * 4; j += TPB) {
        int nl = j >> 2, k4 = j & 3;
        float4 vv = X4[(size_t)(base + nl) * 4 + k4];
        float d = sdinv[nl];
        half4 h;
        h.x = (half_t)(vv.x * d); h.y = (half_t)(vv.y * d);
        h.z = (half_t)(vv.z * d); h.w = (half_t)(vv.w * d);
        G4[(size_t)(base + nl) * 4 + k4] = h;
    }
    if (b == 0 && t < 4) G4[(size_t)n * 4 + t] = half4{0, 0, 0, 0};  // sentinel row
}

// ---------------- fused gather + GEMM conv (conv1, conv2) ----------------
template<int DI, int DO, int R, bool SCALE, bool OUT_HALF, bool WHALF, bool ZSENT>
__global__ void __launch_bounds__(TPB, 4)
k_conv(const int* __restrict__ offs, const unsigned short* __restrict__ nch,
       const unsigned short* __restrict__ ssrc,
       const half_t* __restrict__ G, const float* __restrict__ dinv,
       const float* __restrict__ W, const float* __restrict__ b,
       void* __restrict__ outp, int n) {
    constexpr int CT = DO / 4;
    constexpr int RT = TPB / CT;
    constexpr int TM = RT * R;
    constexpr int K4 = DI / 4;
    constexpr int PX = K4 + 1;
    constexpr int C  = DI / 8;
    static_assert(TM * C == TPB, "gather/gemm tile mismatch");
    __shared__ float4 sW4[WHALF ? 1 : DI * CT];
    __shared__ half4  sWh[WHALF ? DI * CT : 1];
    __shared__ float4 sX4[TM * PX];
    __shared__ int soffs[TM];
    __shared__ unsigned short snch[TM];
    const int tid = threadIdx.x;
    const int r0 = blockIdx.x * TM;

    const float4* Wg = (const float4*)W;
    for (int t = tid; t < DI * CT; t += TPB) {
        float4 w = Wg[t];
        if (WHALF) {
            half4 h;
            h.x = (half_t)w.x; h.y = (half_t)w.y;
            h.z = (half_t)w.z; h.w = (half_t)w.w;
            sWh[t] = h;
        } else {
            sW4[t] = w;
        }
    }
    if (tid < TM) {
        int row = r0 + tid;
        soffs[tid] = (row < n) ? offs[row] : 0;
        snch[tid] = (row < n) ? nch[row] : (unsigned short)0;
    }
    __syncthreads();

    {   // ---- gather ----
        int lrow = tid / C;
        int gc = tid - lrow * C;
        int row = r0 + lrow;
        float8v acc;
#pragma unroll
        for (int q = 0; q < 8; ++q) acc[q] = 0.f;
        if (row < n) {
            const half8* Grow = (const half8*)G;
            const unsigned gcU = (unsigned)gc;
            half8 hs = Grow[(unsigned)row * C + gcU];
#pragma unroll
            for (int q = 0; q < 8; ++q) acc[q] = (float)hs[q];
            const int nchunks = snch[lrow];
            const uint4* sv = (const uint4*)(ssrc + soffs[lrow]);
            int k = 0;
            for (; k + 2 <= nchunks; k += 2) {
                uint4 pa = sv[k];
                uint4 pb = sv[k + 1];
                unsigned a0 = pa.x & 0xFFFFu, a1 = pa.x >> 16;
                unsigned a2 = pa.y & 0xFFFFu, a3 = pa.y >> 16;
                unsigned a4 = pa.z & 0xFFFFu, a5 = pa.z >> 16;
                unsigned a6 = pa.w & 0xFFFFu, a7 = pa.w >> 16;
                unsigned b0 = pb.x & 0xFFFFu, b1 = pb.x >> 16;
                unsigned b2 = pb.y & 0xFFFFu, b3 = pb.y >> 16;
                unsigned b4 = pb.z & 0xFFFFu, b5 = pb.z >> 16;
                unsigned b6 = pb.w & 0xFFFFu, b7 = pb.w >> 16;
                half8 ga0 = Grow[a0 * C + gcU];
                half8 ga1 = Grow[a1 * C + gcU];
                half8 ga2 = Grow[a2 * C + gcU];
                half8 ga3 = Grow[a3 * C + gcU];
                half8 ga4 = Grow[a4 * C + gcU];
                half8 ga5 = Grow[a5 * C + gcU];
                half8 ga6 = Grow[a6 * C + gcU];
                half8 ga7 = Grow[a7 * C + gcU];
                half8 gb0 = Grow[b0 * C + gcU];
                half8 gb1 = Grow[b1 * C + gcU];
                half8 gb2 = Grow[b2 * C + gcU];
                half8 gb3 = Grow[b3 * C + gcU];
                half8 gb4 = Grow[b4 * C + gcU];
                half8 gb5 = Grow[b5 * C + gcU];
                half8 gb6 = Grow[b6 * C + gcU];
                half8 gb7 = Grow[b7 * C + gcU];
#pragma unroll
                for (int q = 0; q < 8; ++q)
                    acc[q] += (((((float)ga0[q] + (float)ga1[q]) + ((float)ga2[q] + (float)ga3[q]))
                             +  (((float)ga4[q] + (float)ga5[q]) + ((float)ga6[q] + (float)ga7[q])))
                             + ((((float)gb0[q] + (float)gb1[q]) + ((float)gb2[q] + (float)gb3[q]))
                             +  (((float)gb4[q] + (float)gb5[q]) + ((float)gb6[q] + (float)gb7[q]))));
            }
            if (k < nchunks) {
                uint4 pk = sv[k];
                unsigned a0 = pk.x & 0xFFFFu, a1 = pk.x >> 16;
                unsigned a2 = pk.y & 0xFFFFu, a3 = pk.y >> 16;
                unsigned a4 = pk.z & 0xFFFFu, a5 = pk.z >> 16;
                unsigned a6 = pk.w & 0xFFFFu, a7 = pk.w >> 16;
                half8 g0 = Grow[a0 * C + gcU];
                half8 g1 = Grow[a1 * C + gcU];
                half8 g2 = Grow[a2 * C + gcU];
                half8 g3 = Grow[a3 * C + gcU];
                half8 g4 = Grow[a4 * C + gcU];
                half8 g5 = Grow[a5 * C + gcU];
                half8 g6 = Grow[a6 * C + gcU];
                half8 g7 = Grow[a7 * C + gcU];
#pragma unroll
                for (int q = 0; q < 8; ++q)
                    acc[q] += (((float)g0[q] + (float)g1[q]) + ((float)g2[q] + (float)g3[q]))
                            + (((float)g4[q] + (float)g5[q]) + ((float)g6[q] + (float)g7[q]));
            }
            float di = dinv[row];
#pragma unroll
            for (int q = 0; q < 8; ++q) acc[q] *= di;
        }
        sX4[lrow * PX + 2 * gc]     = make_float4(acc[0], acc[1], acc[2], acc[3]);
        sX4[lrow * PX + 2 * gc + 1] = make_float4(acc[4], acc[5], acc[6], acc[7]);
    }
    __syncthreads();

    // ---- GEMM ----
    const int c = tid & (CT - 1);
    const int rg = tid / CT;
    const int rbase = rg * R;
    float4 acc[R];
#pragma unroll
    for (int r = 0; r < R; ++r) acc[r] = make_float4(0.f, 0.f, 0.f, 0.f);
#pragma unroll 2
    for (int k4 = 0; k4 < K4; ++k4) {
        float4 xv[R];
#pragma unroll
        for (int r = 0; r < R; ++r) xv[r] = sX4[(rbase + r) * PX + k4];
#pragma unroll
        for (int kk = 0; kk < 4; ++kk) {
            float4 wv;
            if (WHALF) {
                half4 wh = sWh[(k4 * 4 + kk) * CT + c];
                wv = make_float4((float)wh.x, (float)wh.y, (float)wh.z, (float)wh.w);
            } else {
                wv = sW4[(k4 * 4 + kk) * CT + c];
            }
#pragma unroll
            for (int r = 0; r < R; ++r) {
                float xs = (kk == 0) ? xv[r].x : (kk == 1) ? xv[r].y
                         : (kk == 2) ? xv[r].z : xv[r].w;
                acc[r].x += xs * wv.x; acc[r].y += xs * wv.y;
                acc[r].z += xs * wv.z; acc[r].w += xs * wv.w;
            }
        }
    }

    float4 bc = ((const float4*)b)[c];
#pragma unroll
    for (int r = 0; r < R; ++r) {
        int row = r0 + rbase + r;
        if (row < n) {
            float4 o;
            o.x = fmaxf(acc[r].x + bc.x, 0.f);
            o.y = fmaxf(acc[r].y + bc.y, 0.f);
            o.z = fmaxf(acc[r].z + bc.z, 0.f);
            o.w = fmaxf(acc[r].w + bc.w, 0.f);
            if (SCALE) {
                float d = dinv[row];
                o.x *= d; o.y *= d; o.z *= d; o.w *= d;
            }
            if (OUT_HALF) {
                half4 h;
                h.x = (half_t)o.x; h.y = (half_t)o.y;
                h.z = (half_t)o.z; h.w = (half_t)o.w;
                ((half4*)outp)[(size_t)row * CT + c] = h;
            } else {
                ((float4*)outp)[(size_t)row * CT + c] = o;
            }
        }
    }
    if (ZSENT && OUT_HALF && blockIdx.x == 0 && tid < CT)
        ((half4*)outp)[(size_t)n * CT + tid] = half4{0, 0, 0, 0};
}

// ---------------- conv3 (64->128) + fused dense head ----------------
__global__ void __launch_bounds__(TPB, 4)
k_conv3_head(const int* __restrict__ offs, const unsigned short* __restrict__ nch,
             const unsigned short* __restrict__ ssrc,
             const half_t* __restrict__ G, const float* __restrict__ dinv,
             const float* __restrict__ W, const float* __restrict__ b,
             const float* __restrict__ Wl1, const float* __restrict__ bl1,
             const float* __restrict__ Wl2, const float* __restrict__ bl2,
             const float* __restrict__ Wl3, const float* __restrict__ bl3,
             float* __restrict__ out, int n) {
    constexpr int DI = 64, DO = 128, R = 4;
    constexpr int CT = DO / 4;       // 32
    constexpr int TM = (TPB / CT) * R;  // 32 rows/block
    constexpr int K4 = DI / 4;       // 16
    constexpr int PX = K4 + 1;       // 17
    constexpr int C  = DI / 8;       // 8
    constexpr int XP = 136;          // X3 row pitch (halfs): 16B-aligned, bank-spread
    __shared__ union {
        struct { half4 sWh[DI * CT]; float4 sX4[TM * PX]; } g;           // 24.5 KB
        struct { half_t X3[TM * XP]; half_t hW1[128 * 64];
                 float h1[TM * 65]; float h2[TM * 33]; } h;              // 36.8 KB
    } S;
    __shared__ int soffs[TM];
    __shared__ unsigned short snch[TM];
    const int tid = threadIdx.x;
    const int r0 = blockIdx.x * TM;

    const float4* Wg = (const float4*)W;
    for (int t = tid; t < DI * CT; t += TPB) {
        float4 w = Wg[t];
        half4 hh;
        hh.x = (half_t)w.x; hh.y = (half_t)w.y;
        hh.z = (half_t)w.z; hh.w = (half_t)w.w;
        S.g.sWh[t] = hh;
    }
    if (tid < TM) {
        int row = r0 + tid;
        soffs[tid] = (row < n) ? offs[row] : 0;
        snch[tid] = (row < n) ? nch[row] : (unsigned short)0;
    }
    __syncthreads();

    {   // ---- gather (DI=64) ----
        int lrow = tid / C;
        int gc = tid - lrow * C;
        int row = r0 + lrow;
        float8v acc;
#pragma unroll
        for (int q = 0; q < 8; ++q) acc[q] = 0.f;
        if (row < n) {
            const half8* Grow = (const half8*)G;
            const unsigned gcU = (unsigned)gc;
            half8 hs = Grow[(unsigned)row * C + gcU];
#pragma unroll
            for (int q = 0; q < 8; ++q) acc[q] = (float)hs[q];
            const int nchunks = snch[lrow];
            const uint4* sv = (const uint4*)(ssrc + soffs[lrow]);
            int k = 0;
            for (; k + 2 <= nchunks; k += 2) {
                uint4 pa = sv[k];
                uint4 pb = sv[k + 1];
                unsigned a0 = pa.x & 0xFFFFu, a1 = pa.x >> 16;
                unsigned a2 = pa.y & 0xFFFFu, a3 = pa.y >> 16;
                unsigned a4 = pa.z & 0xFFFFu, a5 = pa.z >> 16;
                unsigned a6 = pa.w & 0xFFFFu, a7 = pa.w >> 16;
                unsigned b0 = pb.x & 0xFFFFu, b1 = pb.x >> 16;
                unsigned b2 = pb.y & 0xFFFFu, b3 = pb.y >> 16;
                unsigned b4 = pb.z & 0xFFFFu, b5 = pb.z >> 16;
                unsigned b6 = pb.w & 0xFFFFu, b7 = pb.w >> 16;
                half8 ga0 = Grow[a0 * C + gcU];
                half8 ga1 = Grow[a1 * C + gcU];
                half8 ga2 = Grow[a2 * C + gcU];
                half8 ga3 = Grow[a3 * C + gcU];
                half8 ga4 = Grow[a4 * C + gcU];
                half8 ga5 = Grow[a5 * C + gcU];
                half8 ga6 = Grow[a6 * C + gcU];
                half8 ga7 = Grow[a7 * C + gcU];
                half8 gb0 = Grow[b0 * C + gcU];
                half8 gb1 = Grow[b1 * C + gcU];
                half8 gb2 = Grow[b2 * C + gcU];
                half8 gb3 = Grow[b3 * C + gcU];
                half8 gb4 = Grow[b4 * C + gcU];
                half8 gb5 = Grow[b5 * C + gcU];
                half8 gb6 = Grow[b6 * C + gcU];
                half8 gb7 = Grow[b7 * C + gcU];
#pragma unroll
                for (int q = 0; q < 8; ++q)
                    acc[q] += (((((float)ga0[q] + (float)ga1[q]) + ((float)ga2[q] + (float)ga3[q]))
                             +  (((float)ga4[q] + (float)ga5[q]) + ((float)ga6[q] + (float)ga7[q])))
                             + ((((float)gb0[q] + (float)gb1[q]) + ((float)gb2[q] + (float)gb3[q]))
                             +  (((float)gb4[q] + (float)gb5[q]) + ((float)gb6[q] + (float)gb7[q]))));
            }
            if (k < nchunks) {
                uint4 pk = sv[k];
                unsigned a0 = pk.x & 0xFFFFu, a1 = pk.x >> 16;
                unsigned a2 = pk.y & 0xFFFFu, a3 = pk.y >> 16;
                unsigned a4 = pk.z & 0xFFFFu, a5 = pk.z >> 16;
                unsigned a6 = pk.w & 0xFFFFu, a7 = pk.w >> 16;
                half8 g0 = Grow[a0 * C + gcU];
                half8 g1 = Grow[a1 * C + gcU];
                half8 g2 = Grow[a2 * C + gcU];
                half8 g3 = Grow[a3 * C + gcU];
                half8 g4 = Grow[a4 * C + gcU];
                half8 g5 = Grow[a5 * C + gcU];
                half8 g6 = Grow[a6 * C + gcU];
                half8 g7 = Grow[a7 * C + gcU];
#pragma unroll
                for (int q = 0; q < 8; ++q)
                    acc[q] += (((float)g0[q] + (float)g1[q]) + ((float)g2[q] + (float)g3[q]))
                            + (((float)g4[q] + (float)g5[q]) + ((float)g6[q] + (float)g7[q]));
            }
            float di = dinv[row];
#pragma unroll
            for (int q = 0; q < 8; ++q) acc[q] *= di;
        }
        S.g.sX4[lrow * PX + 2 * gc]     = make_float4(acc[0], acc[1], acc[2], acc[3]);
        S.g.sX4[lrow * PX + 2 * gc + 1] = make_float4(acc[4], acc[5], acc[6], acc[7]);
    }
    __syncthreads();

    // ---- GEMM 64 -> 128 (bias+relu kept in registers) ----
    const int c = tid & (CT - 1);
    const int rg = tid / CT;
    const int rbase = rg * R;
    float4 acc[R];
#pragma unroll
    for (int r = 0; r < R; ++r) acc[r] = make_float4(0.f, 0.f, 0.f, 0.f);
#pragma unroll 2
    for (int k4 = 0; k4 < K4; ++k4) {
        float4 xv[R];
#pragma unroll
        for (int r = 0; r < R; ++r) xv[r] = S.g.sX4[(rbase + r) * PX + k4];
#pragma unroll
        for (int kk = 0; kk < 4; ++kk) {
            half4 wh = S.g.sWh[(k4 * 4 + kk) * CT + c];
            float4 wv = make_float4((float)wh.x, (float)wh.y, (float)wh.z, (float)wh.w);
#pragma unroll
            for (int r = 0; r < R; ++r) {
                float xs = (kk == 0) ? xv[r].x : (kk == 1) ? xv[r].y
                         : (kk == 2) ? xv[r].z : xv[r].w;
                acc[r].x += xs * wv.x; acc[r].y += xs * wv.y;
                acc[r].z += xs * wv.z; acc[r].w += xs * wv.w;
            }
        }
    }
    {
        float4 bc = ((const float4*)b)[c];
#pragma unroll
        for (int r = 0; r < R; ++r) {
            acc[r].x = fmaxf(acc[r].x + bc.x, 0.f);
            acc[r].y = fmaxf(acc[r].y + bc.y, 0.f);
            acc[r].z = fmaxf(acc[r].z + bc.z, 0.f);
            acc[r].w = fmaxf(acc[r].w + bc.w, 0.f);
        }
    }
    __syncthreads();   // all reads of S.g complete; union flips to S.h

    // ---- spill X3 tile to LDS (half) + stage Wl1 (half) ----
#pragma unroll
    for (int r = 0; r < R; ++r) {
        half4 hv;
        hv.x = (half_t)acc[r].x; hv.y = (half_t)acc[r].y;
        hv.z = (half_t)acc[r].z; hv.w = (half_t)acc[r].w;
        *(half4*)&S.h.X3[(rbase + r) * XP + c * 4] = hv;
    }
    for (int t = tid; t < 128 * 64; t += TPB) S.h.hW1[t] = (half_t)Wl1[t];
    __syncthreads();

    // ---- head stage 1: 128 -> 64 ----
    {
        const int c4 = tid & 15;
        const int rowg = tid >> 4;        // 16 groups x 2 rows
        float a1[2][4];
#pragma unroll
        for (int r = 0; r < 2; ++r)
#pragma unroll
            for (int j = 0; j < 4; ++j) a1[r][j] = 0.f;
        for (int k8 = 0; k8 < 16; ++k8) {
            half8 xh[2];
#pragma unroll
            for (int r = 0; r < 2; ++r)
                xh[r] = *(const half8*)&S.h.X3[(rowg * 2 + r) * XP + k8 * 8];
#pragma unroll
            for (int q = 0; q < 8; ++q) {
                int k = k8 * 8 + q;
                half4 w = *(const half4*)&S.h.hW1[k * 64 + c4 * 4];
                float w0 = (float)w.x, w1 = (float)w.y, w2 = (float)w.z, w3 = (float)w.w;
#pragma unroll
                for (int r = 0; r < 2; ++r) {
                    float xs = (float)xh[r][q];
                    a1[r][0] += xs * w0; a1[r][1] += xs * w1;
                    a1[r][2] += xs * w2; a1[r][3] += xs * w3;
                }
            }
        }
        float4 bc = ((const float4*)bl1)[c4];
#pragma unroll
        for (int r = 0; r < 2; ++r) {
            int rl = rowg * 2 + r;
            S.h.h1[rl * 65 + c4 * 4 + 0] = fmaxf(a1[r][0] + bc.x, 0.f);
            S.h.h1[rl * 65 + c4 * 4 + 1] = fmaxf(a1[r][1] + bc.y, 0.f);
            S.h.h1[rl * 65 + c4 * 4 + 2] = fmaxf(a1[r][2] + bc.z, 0.f);
            S.h.h1[rl * 65 + c4 * 4 + 3] = fmaxf(a1[r][3] + bc.w, 0.f);
        }
    }
    __syncthreads();

    // ---- head stage 2: 64 -> 32 (weights fp32 straight from L2) ----
    {
        const int c4 = tid & 7;
        const int rl = tid >> 3;          // 32 rows, 1 each
        float a2[4] = {0.f, 0.f, 0.f, 0.f};
#pragma unroll 4
        for (int k = 0; k < 64; ++k) {
            float4 w = ((const float4*)Wl2)[k * 8 + c4];
            float xs = S.h.h1[rl * 65 + k];
            a2[0] += xs * w.x; a2[1] += xs * w.y;
            a2[2] += xs * w.z; a2[3] += xs * w.w;
        }
        float4 bc = ((const float4*)bl2)[c4];
        S.h.h2[rl * 33 + c4 * 4 + 0] = fmaxf(a2[0] + bc.x, 0.f);
        S.h.h2[rl * 33 + c4 * 4 + 1] = fmaxf(a2[1] + bc.y, 0.f);
        S.h.h2[rl * 33 + c4 * 4 + 2] = fmaxf(a2[2] + bc.z, 0.f);
        S.h.h2[rl * 33 + c4 * 4 + 3] = fmaxf(a2[3] + bc.w, 0.f);
    }
    __syncthreads();

    // ---- head stage 3: 32 -> 16 (first 128 threads) ----
    {
        const int c4 = tid & 3;
        const int rl = tid >> 2;
        if (rl < TM) {
            float s0 = 0.f, s1 = 0.f, s2 = 0.f, s3 = 0.f;
#pragma unroll 4
            for (int k = 0; k < 32; ++k) {
                float4 w = ((const float4*)Wl3)[k * 4 + c4];
                float xs = S.h.h2[rl * 33 + k];
                s0 += xs * w.x; s1 += xs * w.y;
                s2 += xs * w.z; s3 += xs * w.w;
            }
            int row = r0 + rl;
            if (row < n) {
                float4 bc = ((const float4*)bl3)[c4];
                float4 o;
                o.x = fmaxf(s0 + bc.x, 0.f);
                o.y = fmaxf(s1 + bc.y, 0.f);
                o.z = fmaxf(s2 + bc.z, 0.f);
                o.w = fmaxf(s3 + bc.w, 0.f);
                ((float4*)out)[(size_t)row * 4 + c4] = o;
            }
        }
    }
}

extern "C" void kernel_launch(void* const* d_in, const int* in_sizes, int n_in,
                              void* d_out, int out_size, void* d_ws, size_t ws_size,
                              hipStream_t stream) {
    const float* x   = (const float*)d_in[0];
    const int*   ei  = (const int*)d_in[1];
    const float* W1  = (const float*)d_in[2];
    const float* bb1 = (const float*)d_in[3];
    const float* W2  = (const float*)d_in[4];
    const float* bb2 = (const float*)d_in[5];
    const float* W3  = (const float*)d_in[6];
    const float* bb3 = (const float*)d_in[7];
    const float* Wl1 = (const float*)d_in[8];
    const float* bl1 = (const float*)d_in[9];
    const float* Wl2 = (const float*)d_in[10];
    const float* bl2 = (const float*)d_in[11];
    const float* Wl3 = (const float*)d_in[12];
    const float* bl3 = (const float*)d_in[13];
    float* out = (float*)d_out;

    const int n = in_sizes[0] / 16;   // 50000
    const int e = in_sizes[1] / 2;    // 800000
    const int* src = ei;
    const int* dst = ei + e;
    const int nb = cdiv(n, 256);      // 196 coarse buckets

    char* p = (char*)d_ws;
    auto alloc = [&](size_t bytes) {
        char* r = p;
        p += (bytes + 255) & ~(size_t)255;
        return r;
    };
    int*            bcur = (int*)           alloc(1024);                  // 256 ints
    int*            ncnt = (int*)           alloc((size_t)nb * 256 * 4); // contiguous after bcur
    float*          dinv = (float*)         alloc((size_t)n * 4);
    int*            offs = (int*)           alloc((size_t)n * 4);
    unsigned short* nch  = (unsigned short*)alloc((size_t)n * 2);
    unsigned int*   gbuf = (unsigned int*)  alloc((size_t)nb * MAXB * 4);
    unsigned short* ssrc = (unsigned short*)alloc((size_t)nb * MAXB * 2);
    half_t*         H1   = (half_t*)        alloc((size_t)(n + 1) * 64 * 2); // G16/G64
    half_t*         H2   = (half_t*)        alloc((size_t)(n + 1) * 32 * 2);

    hipMemsetAsync(bcur, 0, 1024 + (size_t)nb * 256 * 4, stream);
    k_binscatter<<<cdiv(e, TE), TPB, 0, stream>>>(src, dst, bcur, ncnt, gbuf, e, nb);
    k_csr<<<nb, TPB, 0, stream>>>(gbuf, bcur, ncnt, x, offs, nch, dinv, ssrc, H1, n, nb);

    k_conv<16, 32, 4, true, true, false, true><<<cdiv(n, 128), TPB, 0, stream>>>(
        offs, nch, ssrc, H1, dinv, W1, bb1, H2, n);
    k_conv<32, 64, 4, true, true, false, true><<<cdiv(n, 64), TPB, 0, stream>>>(
        offs, nch, ssrc, H2, dinv, W2, bb2, H1, n);
    k_conv3_head<<<cdiv(n, 32), TPB, 0, stream>>>(
        offs, nch, ssrc, H1, dinv, W3, bb3, Wl1, bl1, Wl2, bl2, Wl3, bl3, out, n);
}

// Round 4
// 204.303 us; speedup vs baseline: 3.5726x; 1.0680x over previous
//
#include <hip/hip_runtime.h>

#define TPB 256
#define TE  2048      // edges per binscatter block
#define MAXB 6144     // fixed bucket capacity (mean 4081, 32 sigma headroom); mult of 8

typedef _Float16 half_t;
typedef _Float16 half4 __attribute__((ext_vector_type(4)));
typedef _Float16 half8 __attribute__((ext_vector_type(8)));
typedef float float8v __attribute__((ext_vector_type(8)));
typedef float f32x4 __attribute__((ext_vector_type(4)));

static inline int cdiv(int a, int b) { return (a + b - 1) / b; }

// r5: scattered 4B stores ~16x write-amplified -> contiguous runs only.
// r12: fixed-capacity buckets kill histogram+scans.
// r14: software grid barriers cost ~100us (L2 wb/inv, non-coherent XCD L2s);
//      kernel boundaries ARE the cheap barrier.
// r15 (R3 counters): conv3_head 62.8us, VALUBusy 48%, MfmaUtil 0 -> the cost
//      is VALU-executed matmul (cvt + scalar FMA). This round: MFMA
//      (f32_16x16x32_f16) for conv3's 64->128 GEMM and head stage1 128->64.
//      A: row=lane&15, k=(lane>>4)*8+i; B: col=lane&15, same k;
//      C/D: col=lane&15, row=(lane>>4)*4+reg. LDS pitches 72/136 halfs keep
//      b128 fragment reads at the free 2-way alias.

__global__ void __launch_bounds__(TPB)
k_binscatter(const int* __restrict__ src, const int* __restrict__ dst,
             int* __restrict__ bcur, int* __restrict__ ncnt,
             unsigned int* __restrict__ gbuf, int e, int nb) {
    __shared__ int lcnt[256], loffs[256], lcur[256], gres[256];
    __shared__ int ss[256];
    __shared__ unsigned int ldata[TE];
    const int tid = threadIdx.x;
    const int base = blockIdx.x * TE;
    const int cnt = min(TE, e - base);
    lcnt[tid] = 0;
    __syncthreads();

    unsigned int myv[TE / TPB];
    int myb[TE / TPB];
#pragma unroll
    for (int k = 0; k < TE / TPB; ++k) {
        int j = tid + k * TPB;
        if (j < cnt) {
            int d = dst[base + j], s = src[base + j];
            int b = d >> 8;
            myv[k] = ((unsigned)b << 24) | ((unsigned)(d & 255) << 16) | (unsigned)s;
            myb[k] = b;
            atomicAdd(&lcnt[b], 1);
            atomicAdd(&ncnt[d], 1);          // global per-node in-degree
        } else myb[k] = -1;
    }
    __syncthreads();
    {
        int v = lcnt[tid];
        ss[tid] = v;
        __syncthreads();
        for (int d = 1; d < 256; d <<= 1) {
            int x2 = (tid >= d) ? ss[tid - d] : 0;
            __syncthreads();
            ss[tid] += x2;
            __syncthreads();
        }
        loffs[tid] = ss[tid] - v;
        lcur[tid] = ss[tid] - v;
    }
    __syncthreads();
    if (tid < nb && lcnt[tid])
        gres[tid] = tid * MAXB + atomicAdd(&bcur[tid], lcnt[tid]);
#pragma unroll
    for (int k = 0; k < TE / TPB; ++k) {
        if (myb[k] >= 0) {
            int p = atomicAdd(&lcur[myb[k]], 1);
            ldata[p] = myv[k];
        }
    }
    __syncthreads();
    for (int j = tid; j < cnt; j += TPB) {        // contiguous per-bucket runs
        unsigned int v = ldata[j];
        int b = v >> 24;
        gbuf[gres[b] + (j - loffs[b])] = v & 0xFFFFFFu;
    }
}

// per-bucket CSR from precomputed degrees: ONE pass over bucket edges.
__global__ void __launch_bounds__(TPB)
k_csr(const unsigned int* __restrict__ gbuf, const int* __restrict__ bcur,
      const int* __restrict__ ncnt, const float* __restrict__ x,
      int* __restrict__ offs, unsigned short* __restrict__ nch,
      float* __restrict__ dinv, unsigned short* __restrict__ ssrc,
      half_t* __restrict__ G, int n, int nb) {
    __shared__ int ss[256], lcur2[256];
    __shared__ float sdinv[256];
    __shared__ unsigned short stage[MAXB];
    const int b = blockIdx.x;
    const int t = threadIdx.x;
    const int s0 = b * MAXB;
    const int m = bcur[b];

    const int v = ncnt[b * 256 + t];              // in-degree (excl self-loop)
    const int pv = (v + 7) & ~7;                  // pad to 8
    ss[t] = pv;
    __syncthreads();
    for (int d = 1; d < 256; d <<= 1) {
        int x2 = (t >= d) ? ss[t - d] : 0;
        __syncthreads();
        ss[t] += x2;
        __syncthreads();
    }
    const int lo = ss[t] - pv;
    lcur2[t] = lo;
    float di = rsqrtf((float)v + 1.0f);           // +1 self-loop
    sdinv[t] = di;
    int node = b * 256 + t;
    if (node < n) {
        offs[node] = s0 + lo;
        nch[node] = (unsigned short)(pv >> 3);
        dinv[node] = di;
    }
    __syncthreads();
    for (int j = t; j < m; j += TPB) {
        unsigned int u = gbuf[s0 + j];
        int p = atomicAdd(&lcur2[(u >> 16) & 255], 1);
        stage[p] = (unsigned short)(u & 0xFFFFu);
    }
    __syncthreads();
    for (int q = lo + v; q < lo + pv; ++q)        // sentinel-fill padding
        stage[q] = (unsigned short)n;
    __syncthreads();
    const int tot = ss[255];
    for (int j = t; j < tot; j += TPB) ssrc[s0 + j] = stage[j];

    // fused scale: G16[node] = x[node] * dinv[node], fp32 -> fp16
    const int base = b * 256;
    const int cn = min(256, n - base);
    const float4* X4 = (const float4*)x;
    half4* G4 = (half4*)G;
    for (int j = t; j < cn * 4; j += TPB) {
        int nl = j >> 2, k4 = j & 3;
        float4 vv = X4[(size_t)(base + nl) * 4 + k4];
        float d = sdinv[nl];
        half4 h;
        h.x = (half_t)(vv.x * d); h.y = (half_t)(vv.y * d);
        h.z = (half_t)(vv.z * d); h.w = (half_t)(vv.w * d);
        G4[(size_t)(base + nl) * 4 + k4] = h;
    }
    if (b == 0 && t < 4) G4[(size_t)n * 4 + t] = half4{0, 0, 0, 0};  // sentinel row
}

// ---------------- fused gather + GEMM conv (conv1, conv2) ----------------
template<int DI, int DO, int R, bool SCALE, bool OUT_HALF, bool WHALF, bool ZSENT>
__global__ void __launch_bounds__(TPB, 4)
k_conv(const int* __restrict__ offs, const unsigned short* __restrict__ nch,
       const unsigned short* __restrict__ ssrc,
       const half_t* __restrict__ G, const float* __restrict__ dinv,
       const float* __restrict__ W, const float* __restrict__ b,
       void* __restrict__ outp, int n) {
    constexpr int CT = DO / 4;
    constexpr int RT = TPB / CT;
    constexpr int TM = RT * R;
    constexpr int K4 = DI / 4;
    constexpr int PX = K4 + 1;
    constexpr int C  = DI / 8;
    static_assert(TM * C == TPB, "gather/gemm tile mismatch");
    __shared__ float4 sW4[WHALF ? 1 : DI * CT];
    __shared__ half4  sWh[WHALF ? DI * CT : 1];
    __shared__ float4 sX4[TM * PX];
    __shared__ int soffs[TM];
    __shared__ unsigned short snch[TM];
    const int tid = threadIdx.x;
    const int r0 = blockIdx.x * TM;

    const float4* Wg = (const float4*)W;
    for (int t = tid; t < DI * CT; t += TPB) {
        float4 w = Wg[t];
        if (WHALF) {
            half4 h;
            h.x = (half_t)w.x; h.y = (half_t)w.y;
            h.z = (half_t)w.z; h.w = (half_t)w.w;
            sWh[t] = h;
        } else {
            sW4[t] = w;
        }
    }
    if (tid < TM) {
        int row = r0 + tid;
        soffs[tid] = (row < n) ? offs[row] : 0;
        snch[tid] = (row < n) ? nch[row] : (unsigned short)0;
    }
    __syncthreads();

    {   // ---- gather ----
        int lrow = tid / C;
        int gc = tid - lrow * C;
        int row = r0 + lrow;
        float8v acc;
#pragma unroll
        for (int q = 0; q < 8; ++q) acc[q] = 0.f;
        if (row < n) {
            const half8* Grow = (const half8*)G;
            const unsigned gcU = (unsigned)gc;
            half8 hs = Grow[(unsigned)row * C + gcU];
#pragma unroll
            for (int q = 0; q < 8; ++q) acc[q] = (float)hs[q];
            const int nchunks = snch[lrow];
            const uint4* sv = (const uint4*)(ssrc + soffs[lrow]);
            int k = 0;
            for (; k + 2 <= nchunks; k += 2) {
                uint4 pa = sv[k];
                uint4 pb = sv[k + 1];
                unsigned a0 = pa.x & 0xFFFFu, a1 = pa.x >> 16;
                unsigned a2 = pa.y & 0xFFFFu, a3 = pa.y >> 16;
                unsigned a4 = pa.z & 0xFFFFu, a5 = pa.z >> 16;
                unsigned a6 = pa.w & 0xFFFFu, a7 = pa.w >> 16;
                unsigned b0 = pb.x & 0xFFFFu, b1 = pb.x >> 16;
                unsigned b2 = pb.y & 0xFFFFu, b3 = pb.y >> 16;
                unsigned b4 = pb.z & 0xFFFFu, b5 = pb.z >> 16;
                unsigned b6 = pb.w & 0xFFFFu, b7 = pb.w >> 16;
                half8 ga0 = Grow[a0 * C + gcU];
                half8 ga1 = Grow[a1 * C + gcU];
                half8 ga2 = Grow[a2 * C + gcU];
                half8 ga3 = Grow[a3 * C + gcU];
                half8 ga4 = Grow[a4 * C + gcU];
                half8 ga5 = Grow[a5 * C + gcU];
                half8 ga6 = Grow[a6 * C + gcU];
                half8 ga7 = Grow[a7 * C + gcU];
                half8 gb0 = Grow[b0 * C + gcU];
                half8 gb1 = Grow[b1 * C + gcU];
                half8 gb2 = Grow[b2 * C + gcU];
                half8 gb3 = Grow[b3 * C + gcU];
                half8 gb4 = Grow[b4 * C + gcU];
                half8 gb5 = Grow[b5 * C + gcU];
                half8 gb6 = Grow[b6 * C + gcU];
                half8 gb7 = Grow[b7 * C + gcU];
#pragma unroll
                for (int q = 0; q < 8; ++q)
                    acc[q] += (((((float)ga0[q] + (float)ga1[q]) + ((float)ga2[q] + (float)ga3[q]))
                             +  (((float)ga4[q] + (float)ga5[q]) + ((float)ga6[q] + (float)ga7[q])))
                             + ((((float)gb0[q] + (float)gb1[q]) + ((float)gb2[q] + (float)gb3[q]))
                             +  (((float)gb4[q] + (float)gb5[q]) + ((float)gb6[q] + (float)gb7[q]))));
            }
            if (k < nchunks) {
                uint4 pk = sv[k];
                unsigned a0 = pk.x & 0xFFFFu, a1 = pk.x >> 16;
                unsigned a2 = pk.y & 0xFFFFu, a3 = pk.y >> 16;
                unsigned a4 = pk.z & 0xFFFFu, a5 = pk.z >> 16;
                unsigned a6 = pk.w & 0xFFFFu, a7 = pk.w >> 16;
                half8 g0 = Grow[a0 * C + gcU];
                half8 g1 = Grow[a1 * C + gcU];
                half8 g2 = Grow[a2 * C + gcU];
                half8 g3 = Grow[a3 * C + gcU];
                half8 g4 = Grow[a4 * C + gcU];
                half8 g5 = Grow[a5 * C + gcU];
                half8 g6 = Grow[a6 * C + gcU];
                half8 g7 = Grow[a7 * C + gcU];
#pragma unroll
                for (int q = 0; q < 8; ++q)
                    acc[q] += (((float)g0[q] + (float)g1[q]) + ((float)g2[q] + (float)g3[q]))
                            + (((float)g4[q] + (float)g5[q]) + ((float)g6[q] + (float)g7[q]));
            }
            float di = dinv[row];
#pragma unroll
            for (int q = 0; q < 8; ++q) acc[q] *= di;
        }
        sX4[lrow * PX + 2 * gc]     = make_float4(acc[0], acc[1], acc[2], acc[3]);
        sX4[lrow * PX + 2 * gc + 1] = make_float4(acc[4], acc[5], acc[6], acc[7]);
    }
    __syncthreads();

    // ---- GEMM ----
    const int c = tid & (CT - 1);
    const int rg = tid / CT;
    const int rbase = rg * R;
    float4 acc[R];
#pragma unroll
    for (int r = 0; r < R; ++r) acc[r] = make_float4(0.f, 0.f, 0.f, 0.f);
#pragma unroll 2
    for (int k4 = 0; k4 < K4; ++k4) {
        float4 xv[R];
#pragma unroll
        for (int r = 0; r < R; ++r) xv[r] = sX4[(rbase + r) * PX + k4];
#pragma unroll
        for (int kk = 0; kk < 4; ++kk) {
            float4 wv;
            if (WHALF) {
                half4 wh = sWh[(k4 * 4 + kk) * CT + c];
                wv = make_float4((float)wh.x, (float)wh.y, (float)wh.z, (float)wh.w);
            } else {
                wv = sW4[(k4 * 4 + kk) * CT + c];
            }
#pragma unroll
            for (int r = 0; r < R; ++r) {
                float xs = (kk == 0) ? xv[r].x : (kk == 1) ? xv[r].y
                         : (kk == 2) ? xv[r].z : xv[r].w;
                acc[r].x += xs * wv.x; acc[r].y += xs * wv.y;
                acc[r].z += xs * wv.z; acc[r].w += xs * wv.w;
            }
        }
    }

    float4 bc = ((const float4*)b)[c];
#pragma unroll
    for (int r = 0; r < R; ++r) {
        int row = r0 + rbase + r;
        if (row < n) {
            float4 o;
            o.x = fmaxf(acc[r].x + bc.x, 0.f);
            o.y = fmaxf(acc[r].y + bc.y, 0.f);
            o.z = fmaxf(acc[r].z + bc.z, 0.f);
            o.w = fmaxf(acc[r].w + bc.w, 0.f);
            if (SCALE) {
                float d = dinv[row];
                o.x *= d; o.y *= d; o.z *= d; o.w *= d;
            }
            if (OUT_HALF) {
                half4 h;
                h.x = (half_t)o.x; h.y = (half_t)o.y;
                h.z = (half_t)o.z; h.w = (half_t)o.w;
                ((half4*)outp)[(size_t)row * CT + c] = h;
            } else {
                ((float4*)outp)[(size_t)row * CT + c] = o;
            }
        }
    }
    if (ZSENT && OUT_HALF && blockIdx.x == 0 && tid < CT)
        ((half4*)outp)[(size_t)n * CT + tid] = half4{0, 0, 0, 0};
}

// ---------------- conv3 (64->128, MFMA) + fused dense head (stage1 MFMA) ----------------
__global__ void __launch_bounds__(TPB, 4)
k_conv3_head(const int* __restrict__ offs, const unsigned short* __restrict__ nch,
             const unsigned short* __restrict__ ssrc,
             const half_t* __restrict__ G, const float* __restrict__ dinv,
             const float* __restrict__ W, const float* __restrict__ b,
             const float* __restrict__ Wl1, const float* __restrict__ bl1,
             const float* __restrict__ Wl2, const float* __restrict__ bl2,
             const float* __restrict__ Wl3, const float* __restrict__ bl3,
             float* __restrict__ out, int n) {
    constexpr int TM = 32;           // rows per block
    constexpr int C  = 8;            // gather: half8 chunks per 64-dim row
    constexpr int XPA = 72;          // X16 pitch (halfs): 144B, 16B-aligned, 2-way bank alias
    constexpr int XPB = 136;         // X3/sW1T pitch (halfs): 272B, same property
    __shared__ __align__(16) union {
        struct { half_t sWhT[128 * XPA]; half_t X16[TM * XPA]; } g;       // 23.0 KB
        struct { half_t X3[TM * XPB]; half_t sW1T[64 * XPB];
                 float h1[TM * 65]; float h2[TM * 33]; } h;               // 37.8 KB
    } S;
    __shared__ int soffs[TM];
    __shared__ unsigned short snch[TM];
    const int tid = threadIdx.x;
    const int r0 = blockIdx.x * TM;
    const int lane = tid & 63;
    const int wv = tid >> 6;         // wave 0..3
    const int lr = lane & 15;        // A-row / B-col / D-col index
    const int kq = lane >> 4;        // k-quarter

    // stage W3^T (f16): W3 is [64 k][128 c] fp32 -> sWhT[c][k]
    {
        const float4* Wg = (const float4*)W;
        for (int t = tid; t < 64 * 32; t += TPB) {
            int k = t >> 5, c4 = t & 31;
            float4 w = Wg[t];
            S.g.sWhT[(c4 * 4 + 0) * XPA + k] = (half_t)w.x;
            S.g.sWhT[(c4 * 4 + 1) * XPA + k] = (half_t)w.y;
            S.g.sWhT[(c4 * 4 + 2) * XPA + k] = (half_t)w.z;
            S.g.sWhT[(c4 * 4 + 3) * XPA + k] = (half_t)w.w;
        }
    }
    if (tid < TM) {
        int row = r0 + tid;
        soffs[tid] = (row < n) ? offs[row] : 0;
        snch[tid] = (row < n) ? nch[row] : (unsigned short)0;
    }
    __syncthreads();

    {   // ---- gather (DI=64) -> X16 f16 ----
        int lrow = tid / C;
        int gc = tid - lrow * C;
        int row = r0 + lrow;
        float8v acc;
#pragma unroll
        for (int q = 0; q < 8; ++q) acc[q] = 0.f;
        if (row < n) {
            const half8* Grow = (const half8*)G;
            const unsigned gcU = (unsigned)gc;
            half8 hs = Grow[(unsigned)row * C + gcU];
#pragma unroll
            for (int q = 0; q < 8; ++q) acc[q] = (float)hs[q];
            const int nchunks = snch[lrow];
            const uint4* sv = (const uint4*)(ssrc + soffs[lrow]);
            int k = 0;
            for (; k + 2 <= nchunks; k += 2) {
                uint4 pa = sv[k];
                uint4 pb = sv[k + 1];
                unsigned a0 = pa.x & 0xFFFFu, a1 = pa.x >> 16;
                unsigned a2 = pa.y & 0xFFFFu, a3 = pa.y >> 16;
                unsigned a4 = pa.z & 0xFFFFu, a5 = pa.z >> 16;
                unsigned a6 = pa.w & 0xFFFFu, a7 = pa.w >> 16;
                unsigned b0 = pb.x & 0xFFFFu, b1 = pb.x >> 16;
                unsigned b2 = pb.y & 0xFFFFu, b3 = pb.y >> 16;
                unsigned b4 = pb.z & 0xFFFFu, b5 = pb.z >> 16;
                unsigned b6 = pb.w & 0xFFFFu, b7 = pb.w >> 16;
                half8 ga0 = Grow[a0 * C + gcU];
                half8 ga1 = Grow[a1 * C + gcU];
                half8 ga2 = Grow[a2 * C + gcU];
                half8 ga3 = Grow[a3 * C + gcU];
                half8 ga4 = Grow[a4 * C + gcU];
                half8 ga5 = Grow[a5 * C + gcU];
                half8 ga6 = Grow[a6 * C + gcU];
                half8 ga7 = Grow[a7 * C + gcU];
                half8 gb0 = Grow[b0 * C + gcU];
                half8 gb1 = Grow[b1 * C + gcU];
                half8 gb2 = Grow[b2 * C + gcU];
                half8 gb3 = Grow[b3 * C + gcU];
                half8 gb4 = Grow[b4 * C + gcU];
                half8 gb5 = Grow[b5 * C + gcU];
                half8 gb6 = Grow[b6 * C + gcU];
                half8 gb7 = Grow[b7 * C + gcU];
#pragma unroll
                for (int q = 0; q < 8; ++q)
                    acc[q] += (((((float)ga0[q] + (float)ga1[q]) + ((float)ga2[q] + (float)ga3[q]))
                             +  (((float)ga4[q] + (float)ga5[q]) + ((float)ga6[q] + (float)ga7[q])))
                             + ((((float)gb0[q] + (float)gb1[q]) + ((float)gb2[q] + (float)gb3[q]))
                             +  (((float)gb4[q] + (float)gb5[q]) + ((float)gb6[q] + (float)gb7[q]))));
            }
            if (k < nchunks) {
                uint4 pk = sv[k];
                unsigned a0 = pk.x & 0xFFFFu, a1 = pk.x >> 16;
                unsigned a2 = pk.y & 0xFFFFu, a3 = pk.y >> 16;
                unsigned a4 = pk.z & 0xFFFFu, a5 = pk.z >> 16;
                unsigned a6 = pk.w & 0xFFFFu, a7 = pk.w >> 16;
                half8 g0 = Grow[a0 * C + gcU];
                half8 g1 = Grow[a1 * C + gcU];
                half8 g2 = Grow[a2 * C + gcU];
                half8 g3 = Grow[a3 * C + gcU];
                half8 g4 = Grow[a4 * C + gcU];
                half8 g5 = Grow[a5 * C + gcU];
                half8 g6 = Grow[a6 * C + gcU];
                half8 g7 = Grow[a7 * C + gcU];
#pragma unroll
                for (int q = 0; q < 8; ++q)
                    acc[q] += (((float)g0[q] + (float)g1[q]) + ((float)g2[q] + (float)g3[q]))
                            + (((float)g4[q] + (float)g5[q]) + ((float)g6[q] + (float)g7[q]));
            }
            float di = dinv[row];
#pragma unroll
            for (int q = 0; q < 8; ++q) acc[q] *= di;
        }
        half8 hv;
#pragma unroll
        for (int q = 0; q < 8; ++q) hv[q] = (half_t)acc[q];
        *(half8*)&S.g.X16[lrow * XPA + gc * 8] = hv;
    }
    __syncthreads();

    // ---- GEMM 64->128 via MFMA: wave wv owns cols [wv*32, wv*32+32) ----
    f32x4 acc3[2][2];               // [mt][nt]
#pragma unroll
    for (int mt = 0; mt < 2; ++mt)
#pragma unroll
        for (int nt = 0; nt < 2; ++nt) acc3[mt][nt] = f32x4{0.f, 0.f, 0.f, 0.f};
#pragma unroll
    for (int ks = 0; ks < 2; ++ks) {
        half8 a0 = *(const half8*)&S.g.X16[lr * XPA + ks * 32 + kq * 8];
        half8 a1 = *(const half8*)&S.g.X16[(lr + 16) * XPA + ks * 32 + kq * 8];
        half8 b0 = *(const half8*)&S.g.sWhT[(wv * 32 + lr) * XPA + ks * 32 + kq * 8];
        half8 b1 = *(const half8*)&S.g.sWhT[(wv * 32 + 16 + lr) * XPA + ks * 32 + kq * 8];
        acc3[0][0] = __builtin_amdgcn_mfma_f32_16x16x32_f16(a0, b0, acc3[0][0], 0, 0, 0);
        acc3[0][1] = __builtin_amdgcn_mfma_f32_16x16x32_f16(a0, b1, acc3[0][1], 0, 0, 0);
        acc3[1][0] = __builtin_amdgcn_mfma_f32_16x16x32_f16(a1, b0, acc3[1][0], 0, 0, 0);
        acc3[1][1] = __builtin_amdgcn_mfma_f32_16x16x32_f16(a1, b1, acc3[1][1], 0, 0, 0);
    }
    const float bc30 = b[wv * 32 + lr];
    const float bc31 = b[wv * 32 + 16 + lr];
    __syncthreads();                 // all g-union reads complete

    // ---- X3 tile (f16) + stage Wl1^T (f16): Wl1 is [128 k][64 c] fp32 ----
#pragma unroll
    for (int mt = 0; mt < 2; ++mt)
#pragma unroll
        for (int nt = 0; nt < 2; ++nt) {
            float bb = nt ? bc31 : bc30;
#pragma unroll
            for (int j = 0; j < 4; ++j) {
                float v = fmaxf(acc3[mt][nt][j] + bb, 0.f);
                S.h.X3[(mt * 16 + kq * 4 + j) * XPB + wv * 32 + nt * 16 + lr] = (half_t)v;
            }
        }
    {
        const float4* W1g = (const float4*)Wl1;
        for (int t = tid; t < 128 * 16; t += TPB) {
            int k = t >> 4, c4 = t & 15;
            float4 w = W1g[t];
            S.h.sW1T[(c4 * 4 + 0) * XPB + k] = (half_t)w.x;
            S.h.sW1T[(c4 * 4 + 1) * XPB + k] = (half_t)w.y;
            S.h.sW1T[(c4 * 4 + 2) * XPB + k] = (half_t)w.z;
            S.h.sW1T[(c4 * 4 + 3) * XPB + k] = (half_t)w.w;
        }
    }
    __syncthreads();

    // ---- head stage 1: 128 -> 64 via MFMA: wave wv owns cols [wv*16, wv*16+16) ----
    f32x4 h1a[2];
    h1a[0] = f32x4{0.f, 0.f, 0.f, 0.f};
    h1a[1] = f32x4{0.f, 0.f, 0.f, 0.f};
#pragma unroll
    for (int ks = 0; ks < 4; ++ks) {
        half8 a0 = *(const half8*)&S.h.X3[lr * XPB + ks * 32 + kq * 8];
        half8 a1 = *(const half8*)&S.h.X3[(lr + 16) * XPB + ks * 32 + kq * 8];
        half8 bb = *(const half8*)&S.h.sW1T[(wv * 16 + lr) * XPB + ks * 32 + kq * 8];
        h1a[0] = __builtin_amdgcn_mfma_f32_16x16x32_f16(a0, bb, h1a[0], 0, 0, 0);
        h1a[1] = __builtin_amdgcn_mfma_f32_16x16x32_f16(a1, bb, h1a[1], 0, 0, 0);
    }
    {
        float bb = bl1[wv * 16 + lr];
#pragma unroll
        for (int mt = 0; mt < 2; ++mt)
#pragma unroll
            for (int j = 0; j < 4; ++j)
                S.h.h1[(mt * 16 + kq * 4 + j) * 65 + wv * 16 + lr] =
                    fmaxf(h1a[mt][j] + bb, 0.f);
    }
    __syncthreads();

    // ---- head stage 2: 64 -> 32 (weights fp32 straight from L2) ----
    {
        const int c4 = tid & 7;
        const int rl = tid >> 3;          // 32 rows, 1 each
        float a2[4] = {0.f, 0.f, 0.f, 0.f};
#pragma unroll 4
        for (int k = 0; k < 64; ++k) {
            float4 w = ((const float4*)Wl2)[k * 8 + c4];
            float xs = S.h.h1[rl * 65 + k];
            a2[0] += xs * w.x; a2[1] += xs * w.y;
            a2[2] += xs * w.z; a2[3] += xs * w.w;
        }
        float4 bc = ((const float4*)bl2)[c4];
        S.h.h2[rl * 33 + c4 * 4 + 0] = fmaxf(a2[0] + bc.x, 0.f);
        S.h.h2[rl * 33 + c4 * 4 + 1] = fmaxf(a2[1] + bc.y, 0.f);
        S.h.h2[rl * 33 + c4 * 4 + 2] = fmaxf(a2[2] + bc.z, 0.f);
        S.h.h2[rl * 33 + c4 * 4 + 3] = fmaxf(a2[3] + bc.w, 0.f);
    }
    __syncthreads();

    // ---- head stage 3: 32 -> 16 (first 128 threads) ----
    {
        const int c4 = tid & 3;
        const int rl = tid >> 2;
        if (rl < TM) {
            float s0 = 0.f, s1 = 0.f, s2 = 0.f, s3 = 0.f;
#pragma unroll 4
            for (int k = 0; k < 32; ++k) {
                float4 w = ((const float4*)Wl3)[k * 4 + c4];
                float xs = S.h.h2[rl * 33 + k];
                s0 += xs * w.x; s1 += xs * w.y;
                s2 += xs * w.z; s3 += xs * w.w;
            }
            int row = r0 + rl;
            if (row < n) {
                float4 bc = ((const float4*)bl3)[c4];
                float4 o;
                o.x = fmaxf(s0 + bc.x, 0.f);
                o.y = fmaxf(s1 + bc.y, 0.f);
                o.z = fmaxf(s2 + bc.z, 0.f);
                o.w = fmaxf(s3 + bc.w, 0.f);
                ((float4*)out)[(size_t)row * 4 + c4] = o;
            }
        }
    }
}

extern "C" void kernel_launch(void* const* d_in, const int* in_sizes, int n_in,
                              void* d_out, int out_size, void* d_ws, size_t ws_size,
                              hipStream_t stream) {
    const float* x   = (const float*)d_in[0];
    const int*   ei  = (const int*)d_in[1];
    const float* W1  = (const float*)d_in[2];
    const float* bb1 = (const float*)d_in[3];
    const float* W2  = (const float*)d_in[4];
    const float* bb2 = (const float*)d_in[5];
    const float* W3  = (const float*)d_in[6];
    const float* bb3 = (const float*)d_in[7];
    const float* Wl1 = (const float*)d_in[8];
    const float* bl1 = (const float*)d_in[9];
    const float* Wl2 = (const float*)d_in[10];
    const float* bl2 = (const float*)d_in[11];
    const float* Wl3 = (const float*)d_in[12];
    const float* bl3 = (const float*)d_in[13];
    float* out = (float*)d_out;

    const int n = in_sizes[0] / 16;   // 50000
    const int e = in_sizes[1] / 2;    // 800000
    const int* src = ei;
    const int* dst = ei + e;
    const int nb = cdiv(n, 256);      // 196 coarse buckets

    char* p = (char*)d_ws;
    auto alloc = [&](size_t bytes) {
        char* r = p;
        p += (bytes + 255) & ~(size_t)255;
        return r;
    };
    int*            bcur = (int*)           alloc(1024);                  // 256 ints
    int*            ncnt = (int*)           alloc((size_t)nb * 256 * 4); // contiguous after bcur
    float*          dinv = (float*)         alloc((size_t)n * 4);
    int*            offs = (int*)           alloc((size_t)n * 4);
    unsigned short* nch  = (unsigned short*)alloc((size_t)n * 2);
    unsigned int*   gbuf = (unsigned int*)  alloc((size_t)nb * MAXB * 4);
    unsigned short* ssrc = (unsigned short*)alloc((size_t)nb * MAXB * 2);
    half_t*         H1   = (half_t*)        alloc((size_t)(n + 1) * 64 * 2); // G16/G64
    half_t*         H2   = (half_t*)        alloc((size_t)(n + 1) * 32 * 2);

    hipMemsetAsync(bcur, 0, 1024 + (size_t)nb * 256 * 4, stream);
    k_binscatter<<<cdiv(e, TE), TPB, 0, stream>>>(src, dst, bcur, ncnt, gbuf, e, nb);
    k_csr<<<nb, TPB, 0, stream>>>(gbuf, bcur, ncnt, x, offs, nch, dinv, ssrc, H1, n, nb);

    k_conv<16, 32, 4, true, true, false, true><<<cdiv(n, 128), TPB, 0, stream>>>(
        offs, nch, ssrc, H1, dinv, W1, bb1, H2, n);
    k_conv<32, 64, 4, true, true, false, true><<<cdiv(n, 64), TPB, 0, stream>>>(
        offs, nch, ssrc, H2, dinv, W2, bb2, H1, n);
    k_conv3_head<<<cdiv(n, 32), TPB, 0, stream>>>(
        offs, nch, ssrc, H1, dinv, W3, bb3, Wl1, bl1, Wl2, bl2, Wl3, bl3, out, n);
}